// Round 12
// baseline (368.564 us; speedup 1.0000x reference)
//
#include <hip/hip_runtime.h>

typedef unsigned short u16;
typedef __bf16 bf16x8 __attribute__((ext_vector_type(8)));
typedef __bf16 bf16x4 __attribute__((ext_vector_type(4)));
typedef float f32x4 __attribute__((ext_vector_type(4)));
typedef float f32x16 __attribute__((ext_vector_type(16)));
typedef unsigned u32x2 __attribute__((ext_vector_type(2)));

#define AS1 __attribute__((address_space(1)))
#define AS3 __attribute__((address_space(3)))

__device__ __forceinline__ void gload_lds16(const void* g, void* l) {
  __builtin_amdgcn_global_load_lds((const AS1 void*)g, (AS3 void*)l, 16, 0, 0);
}

__device__ __forceinline__ f32x4 mfma16(bf16x8 a, bf16x8 b, f32x4 c) {
  return __builtin_amdgcn_mfma_f32_16x16x32_bf16(a, b, c, 0, 0, 0);
}
__device__ __forceinline__ f32x16 mfma32(bf16x8 a, bf16x8 b, f32x16 c) {
  return __builtin_amdgcn_mfma_f32_32x32x16_bf16(a, b, c, 0, 0, 0);
}

__device__ __forceinline__ float rsum16(f32x16 v) {
  float a0 = v[0] + v[1],  a1 = v[2] + v[3];
  float a2 = v[4] + v[5],  a3 = v[6] + v[7];
  float a4 = v[8] + v[9],  a5 = v[10] + v[11];
  float a6 = v[12] + v[13], a7 = v[14] + v[15];
  return ((a0 + a1) + (a2 + a3)) + ((a4 + a5) + (a6 + a7));
}

// P^T redistribution: f32x16 (one 32x32 tile's k-rows) -> two B-frags via
// cvt pairs + permlane32_swap.
__device__ __forceinline__ void pack2(const f32x16& st, bf16x8& f0, bf16x8& f1) {
  unsigned pk[8];
#pragma unroll
  for (int p = 0; p < 8; p++) {
    union { __bf16 h[2]; unsigned u; } cv;
    cv.h[0] = (__bf16)st[2 * p];
    cv.h[1] = (__bf16)st[2 * p + 1];
    pk[p] = cv.u;
  }
  u32x2 ra = __builtin_amdgcn_permlane32_swap(pk[0], pk[2], false, false);
  u32x2 rb = __builtin_amdgcn_permlane32_swap(pk[1], pk[3], false, false);
  u32x2 rc = __builtin_amdgcn_permlane32_swap(pk[4], pk[6], false, false);
  u32x2 rd = __builtin_amdgcn_permlane32_swap(pk[5], pk[7], false, false);
  union { unsigned u[4]; bf16x8 v; } a, b;
  a.u[0] = ra[0]; a.u[1] = rb[0]; a.u[2] = ra[1]; a.u[3] = rb[1];
  b.u[0] = rc[0]; b.u[1] = rd[0]; b.u[2] = rc[1]; b.u[3] = rd[1];
  f0 = a.v; f1 = b.v;
}

// 0.125 * log2(e): folded into Q at GEMM epilogue so S^T is directly exp2-able.
#define QSCALE 0.18033688011112042f

// ---------------- fused fp32 -> bf16 convert (single launch, 3 ranges) ----
__global__ __launch_bounds__(256) void k_cvt3(const float* __restrict__ s0, u16* __restrict__ d0, int n0,
                                              const float* __restrict__ s1, u16* __restrict__ d1, int n1,
                                              const float* __restrict__ s2, u16* __restrict__ d2, int n2) {
  int g = (blockIdx.x * 256 + threadIdx.x) * 8;
  const float* src;
  u16* dst;
  int i;
  if (g < n0) { src = s0; dst = d0; i = g; }
  else if (g < n0 + n1) { src = s1; dst = d1; i = g - n0; }
  else if (g < n0 + n1 + n2) { src = s2; dst = d2; i = g - n0 - n1; }
  else return;
  float4 a = *(const float4*)(src + i);
  float4 b = *(const float4*)(src + i + 4);
  union { bf16x8 v; uint4 q; } o;
  o.v[0] = (__bf16)a.x; o.v[1] = (__bf16)a.y; o.v[2] = (__bf16)a.z; o.v[3] = (__bf16)a.w;
  o.v[4] = (__bf16)b.x; o.v[5] = (__bf16)b.y; o.v[6] = (__bf16)b.z; o.v[7] = (__bf16)b.w;
  *(uint4*)(dst + i) = o.q;
}

// ---------------- big-tile GEMM template (unchanged from round 10) --------
template <int MODE, int BXN>
__global__ __launch_bounds__(512, 2) void k_gemm_big(
    const u16* __restrict__ A, const u16* __restrict__ W,
    const float* __restrict__ bias, float* __restrict__ Cout,
    u16* __restrict__ Qo, u16* __restrict__ Ko, u16* __restrict__ Vo) {
  __shared__ __align__(16) u16 LDS[2][6 * 4096];  // 96 KB

  const int t = threadIdx.x;
  const int lane = t & 63;
  const int w = t >> 6;
  const int wm = w >> 1;
  const int wn = w & 1;
  const int lr = lane & 15;
  const int hi = lane >> 4;

  const int TOT = BXN * 32;
  const int flat = blockIdx.x;
  const int nb = (flat & 7) * (TOT >> 3) + (flat >> 3);
  const int by = nb / BXN;
  const int bx = nb - by * BXN;
  const int m0 = by * 256;
  const int n0 = bx * 128;

  const int tt = t & 255;
  const int g = t >> 8;
  const int tu = (tt & 15) ^ (tt >> 4);
  const int sro = (tu >> 3) * 32 + (tt >> 4);
  const int scol = (tu & 7) * 8;

  auto STAGE = [&](int buf, int kt, int pLo, int pHi) {
    for (int p = pLo; p < pHi; ++p) {
      int st = p * 2 + g;
      const u16* base = (st < 4) ? (A + (size_t)(m0 + st * 64) * 1024)
                                 : (W + (size_t)(n0 + (st - 4) * 64) * 1024);
#pragma unroll
      for (int i = 0; i < 2; ++i)
        gload_lds16(base + (size_t)(sro + i * 16) * 1024 + kt * 64 + scol,
                    &LDS[buf][st * 4096 + i * 2048 + tt * 8]);
    }
  };

  f32x4 acc[4][4] = {};

  STAGE(0, 0, 0, 3);

  for (int kt = 0; kt < 16; ++kt) {
    const int cur = kt & 1;
    asm volatile("s_waitcnt vmcnt(0)" ::: "memory");
    __builtin_amdgcn_sched_barrier(0);
    __builtin_amdgcn_s_barrier();          // B1
    __builtin_amdgcn_sched_barrier(0);

    const u16* ab = &LDS[cur][wm * 4096];
    const u16* bb = &LDS[cur][(4 + wn) * 4096];

#pragma unroll
    for (int ks = 0; ks < 2; ++ks) {
      bf16x8 af[4], bfr[4];
#pragma unroll
      for (int mi = 0; mi < 4; ++mi)
        af[mi] = *(const bf16x8*)(ab + ((mi & 1) * 16 + lr) * 128 +
                                  (((ks * 4 + hi + 8 * (mi >> 1)) ^ lr) << 3));
#pragma unroll
      for (int ni = 0; ni < 4; ++ni)
        bfr[ni] = *(const bf16x8*)(bb + ((ni & 1) * 16 + lr) * 128 +
                                   (((ks * 4 + hi + 8 * (ni >> 1)) ^ lr) << 3));
      if (kt + 1 < 16) STAGE(cur ^ 1, kt + 1, ks ? 2 : 0, ks ? 3 : 2);
      asm volatile("s_waitcnt lgkmcnt(0)" ::: "memory");
      __builtin_amdgcn_sched_barrier(0);
      __builtin_amdgcn_s_setprio(1);
#pragma unroll
      for (int mi = 0; mi < 4; ++mi)
#pragma unroll
        for (int ni = 0; ni < 4; ++ni)
          acc[mi][ni] = mfma16(bfr[ni], af[mi], acc[mi][ni]);  // swapped
      __builtin_amdgcn_s_setprio(0);
      __builtin_amdgcn_sched_barrier(0);
      if (ks == 0) __builtin_amdgcn_s_barrier();   // B2: phase pacing
    }
  }

  f32x4 bv[4];
#pragma unroll
  for (int ni = 0; ni < 4; ++ni)
    bv[ni] = *(const f32x4*)(bias + n0 + wn * 64 + ni * 16 + hi * 4);

  if (MODE == 0) {
    const int N = BXN * 128;
#pragma unroll
    for (int mi = 0; mi < 4; ++mi) {
      const int m = m0 + wm * 64 + mi * 16 + lr;
#pragma unroll
      for (int ni = 0; ni < 4; ++ni) {
        f32x4 o = acc[mi][ni] + bv[ni];
        *(f32x4*)(Cout + (size_t)m * N + n0 + wn * 64 + ni * 16 + hi * 4) = o;
      }
    }
  } else {
    const int bb16 = m0 >> 11;
    const int sb = (m0 & 2047) + wm * 64;
    const int which = n0 >> 10;
    const int h = ((n0 & 1023) >> 6) + wn;

    if (which < 2) {
      const float scl = (which == 0) ? QSCALE : 1.0f;
      u16* dst = ((which == 0) ? Qo : Ko) + ((size_t)(bb16 * 16 + h) * 2048) * 64;
#pragma unroll
      for (int mi = 0; mi < 4; ++mi) {
        const int s = sb + mi * 16 + lr;
#pragma unroll
        for (int ni = 0; ni < 4; ++ni) {
          bf16x4 pk;
#pragma unroll
          for (int j = 0; j < 4; ++j)
            pk[j] = (__bf16)((acc[mi][ni][j] + bv[ni][j]) * scl);
          *(bf16x4*)(dst + (size_t)s * 64 + ni * 16 + hi * 4) = pk;
        }
      }
    } else {
      __syncthreads();
      u16* scr = &LDS[0][0] + w * 4608;
#pragma unroll
      for (int mi = 0; mi < 4; ++mi)
#pragma unroll
        for (int ni = 0; ni < 4; ++ni)
#pragma unroll
          for (int j = 0; j < 4; ++j) {
            union { __bf16 b; u16 u; } cv;
            cv.b = (__bf16)(acc[mi][ni][j] + bv[ni][j]);
            scr[(ni * 16 + hi * 4 + j) * 72 + mi * 16 + lr] = cv.u;
          }
      asm volatile("s_waitcnt lgkmcnt(0)" ::: "memory");
      __builtin_amdgcn_sched_barrier(0);
      u16* dst = Vo + ((size_t)((bb16 * 16 + h) * 64 + lane)) * 2048 + sb;
#pragma unroll
      for (int mc = 0; mc < 8; ++mc) {
        bf16x8 vv = *(const bf16x8*)(scr + lane * 72 + mc * 8);
        *(bf16x8*)(dst + mc * 8) = vv;
      }
    }
  }
}

// ---------------- flash attention: tile-level double pipeline (T15) -------
// Substep s handles {QK^T+exp2+pack of tile s+1} and {PV of tile s with the
// P packed last substep}: the QK^T->exp2 and exp2->PV dependencies straddle
// substeps, so PV MFMAs interleave with exp2/pack VALU within one wave.
// Explicit pair-loop keeps pfA/pfB statically named (rule #20). 32 q/wave,
// 4 blocks/CU. Single barrier per substep; stage-after-barrier writes buffers
// whose readers all precede the barrier (r6-proven).
__global__ __launch_bounds__(256, 4) void k_attn(const u16* __restrict__ Q,
                                                 const u16* __restrict__ K,
                                                 const u16* __restrict__ Vt,
                                                 u16* __restrict__ ctx) {
  __shared__ __align__(16) u16 Ks[2][64 * 64];
  __shared__ __align__(16) u16 Vs[2][64 * 64];

  const int t = threadIdx.x;
  const int lane = t & 63;
  const int w = t >> 6;
  const int r31 = lane & 31;
  const int hw = lane >> 5;

  const int bid = blockIdx.x;
  const int nb = (bid & 7) * 128 + (bid >> 3);
  const int bh = nb >> 4;
  const int q0 = (nb & 15) * 128;

  const u16* qp = Q + (size_t)bh * 2048 * 64;
  const u16* kp = K + (size_t)bh * 2048 * 64;
  const u16* vp = Vt + (size_t)bh * 64 * 2048;

  const int tu = (t & 15) ^ (t >> 4);
  const int srow = (tu >> 3) * 32 + (t >> 4);
  const int scol = (tu & 7) * 8;

  auto stageK = [&](int kt, u16* dst) {
#pragma unroll
    for (int i = 0; i < 2; i++)
      gload_lds16(kp + (size_t)(kt * 64 + srow + i * 16) * 64 + scol,
                  dst + i * 2048 + t * 8);
  };
  auto stageV = [&](int kt, u16* dst) {
#pragma unroll
    for (int i = 0; i < 2; i++)
      gload_lds16(vp + (size_t)(srow + i * 16) * 2048 + kt * 64 + scol,
                  dst + i * 2048 + t * 8);
  };

  bf16x8 aq[4];
  const u16* qrow = qp + (size_t)(q0 + w * 32 + r31) * 64 + hw * 8;
#pragma unroll
  for (int kd = 0; kd < 4; kd++) aq[kd] = *(const bf16x8*)(qrow + kd * 16);

  const f32x16 Z = {};
  f32x16 o0 = {}, o1 = {};
  float l = 0.f;
  bf16x8 pfA[4], pfB[4];

  // one 32x32 half of QK^T: MFMA chain -> exp2 -> pack; returns partial rowsum
  auto HALF = [&](const u16* kb, int base, bf16x8& f0, bf16x8& f1) -> float {
    f32x16 s;
    {
      bf16x8 ka = *(const bf16x8*)(kb + r31 * 128 + (((base + hw) ^ (r31 & 15)) << 3));
      s = mfma32(ka, aq[0], Z);
    }
#pragma unroll
    for (int kd = 1; kd < 4; kd++) {
      bf16x8 ka = *(const bf16x8*)(kb + r31 * 128 + (((base + kd * 2 + hw) ^ (r31 & 15)) << 3));
      s = mfma32(ka, aq[kd], s);
    }
#pragma unroll
    for (int e = 0; e < 16; e++) s[e] = __builtin_amdgcn_exp2f(s[e]);
    pack2(s, f0, f1);
    return rsum16(s);
  };

  auto PV = [&](const u16* vb, bf16x8 (&pf)[4]) {
    __builtin_amdgcn_s_setprio(1);
#pragma unroll
    for (int kap = 0; kap < 4; kap++) {
      bf16x8 v0 = *(const bf16x8*)(vb + r31 * 128 + (((kap * 2 + hw) ^ (r31 & 15)) << 3));
      bf16x8 v1 = *(const bf16x8*)(vb + r31 * 128 + (((8 + kap * 2 + hw) ^ (r31 & 15)) << 3));
      o0 = mfma32(v0, pf[kap], o0);
      o1 = mfma32(v1, pf[kap], o1);
    }
    __builtin_amdgcn_s_setprio(0);
  };

  // prologue: stage K0,K1,V0; QK^T(0) -> pfA
  stageK(0, Ks[0]);
  stageK(1, Ks[1]);
  stageV(0, Vs[0]);
  asm volatile("s_waitcnt vmcnt(0)" ::: "memory");
  __builtin_amdgcn_sched_barrier(0);
  __builtin_amdgcn_s_barrier();
  __builtin_amdgcn_sched_barrier(0);
  {
    float rs = HALF(Ks[0], 0, pfA[0], pfA[1]);
    rs += HALF(Ks[0], 8, pfA[2], pfA[3]);
    rs += __shfl_xor(rs, 32);
    l += rs;
  }

  // substep: barrier; stage K(kS),V(vS); QK^T(next) -> pfMake; PV(cur, pfUse)
  auto SUB = [&](int kS, u16* kD, int vS, u16* vD, const u16* kR, const u16* vR,
                 bf16x8 (&pfUse)[4], bf16x8 (&pfMake)[4], bool doQ) {
    asm volatile("s_waitcnt vmcnt(0)" ::: "memory");
    __builtin_amdgcn_sched_barrier(0);
    __builtin_amdgcn_s_barrier();
    __builtin_amdgcn_sched_barrier(0);
    if (kS < 32) stageK(kS, kD);
    if (vS < 32) stageV(vS, vD);
    if (doQ) {
      float rs = HALF(kR, 0, pfMake[0], pfMake[1]);
      rs += HALF(kR, 8, pfMake[2], pfMake[3]);
      rs += __shfl_xor(rs, 32);
      l += rs;
    }
    PV(vR, pfUse);
  };

  for (int k = 0; k < 16; ++k) {
    // tiles: PV(2k) w/ pfA; QK^T(2k+1)->pfB; stage K(2k+2)->Ks0, V(2k+1)->Vs1
    SUB(2 * k + 2, Ks[0], 2 * k + 1, Vs[1], Ks[1], Vs[0], pfA, pfB, true);
    // tiles: PV(2k+1) w/ pfB; QK^T(2k+2)->pfA; stage K(2k+3)->Ks1, V(2k+2)->Vs0
    SUB(2 * k + 3, Ks[1], 2 * k + 2, Vs[0], Ks[0], Vs[1], pfB, pfA, k < 15);
  }

  const int bb = bh >> 4, h = bh & 15;
  const float inv = 1.0f / l;
  const size_t base = (size_t)(bb * 2048 + q0 + w * 32 + r31) * 1024 + h * 64;
#pragma unroll
  for (int g = 0; g < 4; g++) {
    bf16x4 p0, p1;
#pragma unroll
    for (int j = 0; j < 4; j++) {
      p0[j] = (__bf16)(o0[g * 4 + j] * inv);
      p1[j] = (__bf16)(o1[g * 4 + j] * inv);
    }
    *(bf16x4*)(ctx + base + g * 8 + hw * 4) = p0;
    *(bf16x4*)(ctx + base + 32 + g * 8 + hw * 4) = p1;
  }
}

extern "C" void kernel_launch(void* const* d_in, const int* in_sizes, int n_in,
                              void* d_out, int out_size, void* d_ws, size_t ws_size,
                              hipStream_t stream) {
  const float* x = (const float*)d_in[0];
  const float* qkv_w = (const float*)d_in[1];
  const float* qkv_b = (const float*)d_in[2];
  const float* out_w = (const float*)d_in[3];
  const float* out_b = (const float*)d_in[4];
  float* out = (float*)d_out;
  char* ws = (char*)d_ws;

  u16* xb    = (u16*)(ws + 0);          // 16 MB (later: ctx)
  u16* wqkvb = (u16*)(ws + 16777216);   // 6 MB
  u16* wob   = (u16*)(ws + 23068672);   // 2 MB
  u16* Qb    = (u16*)(ws + 25165824);   // 16 MB
  u16* Kb    = (u16*)(ws + 41943040);   // 16 MB
  u16* Vtb   = (u16*)(ws + 58720256);   // 16 MB, [BH,64,S]
  u16* ctx   = xb;

  k_cvt3<<<6144, 256, 0, stream>>>(x, xb, 8388608,
                                   qkv_w, wqkvb, 3145728,
                                   out_w, wob, 1048576);

  k_gemm_big<1, 24><<<768, 512, 0, stream>>>(xb, wqkvb, qkv_b, nullptr,
                                             Qb, Kb, Vtb);
  k_attn<<<1024, 256, 0, stream>>>(Qb, Kb, Vtb, ctx);
  k_gemm_big<0, 8><<<256, 512, 0, stream>>>(ctx, wob, out_b, out,
                                            nullptr, nullptr, nullptr);
}

// Round 13
// 195.608 us; speedup vs baseline: 1.8842x; 1.8842x over previous
//
#include <hip/hip_runtime.h>

typedef unsigned short u16;
typedef __bf16 bf16x8 __attribute__((ext_vector_type(8)));
typedef __bf16 bf16x4 __attribute__((ext_vector_type(4)));
typedef float f32x4 __attribute__((ext_vector_type(4)));
typedef float f32x16 __attribute__((ext_vector_type(16)));
typedef unsigned u32x2 __attribute__((ext_vector_type(2)));

#define AS1 __attribute__((address_space(1)))
#define AS3 __attribute__((address_space(3)))

__device__ __forceinline__ void gload_lds16(const void* g, void* l) {
  __builtin_amdgcn_global_load_lds((const AS1 void*)g, (AS3 void*)l, 16, 0, 0);
}

__device__ __forceinline__ f32x4 mfma16(bf16x8 a, bf16x8 b, f32x4 c) {
  return __builtin_amdgcn_mfma_f32_16x16x32_bf16(a, b, c, 0, 0, 0);
}
__device__ __forceinline__ f32x16 mfma32(bf16x8 a, bf16x8 b, f32x16 c) {
  return __builtin_amdgcn_mfma_f32_32x32x16_bf16(a, b, c, 0, 0, 0);
}

// 0.125 * log2(e): folded into Q at GEMM epilogue so S^T is directly exp2-able.
#define QSCALE 0.18033688011112042f

// ---------------- fused fp32 -> bf16 convert (single launch, 3 ranges) ----
__global__ __launch_bounds__(256) void k_cvt3(const float* __restrict__ s0, u16* __restrict__ d0, int n0,
                                              const float* __restrict__ s1, u16* __restrict__ d1, int n1,
                                              const float* __restrict__ s2, u16* __restrict__ d2, int n2) {
  int g = (blockIdx.x * 256 + threadIdx.x) * 8;
  const float* src;
  u16* dst;
  int i;
  if (g < n0) { src = s0; dst = d0; i = g; }
  else if (g < n0 + n1) { src = s1; dst = d1; i = g - n0; }
  else if (g < n0 + n1 + n2) { src = s2; dst = d2; i = g - n0 - n1; }
  else return;
  float4 a = *(const float4*)(src + i);
  float4 b = *(const float4*)(src + i + 4);
  union { bf16x8 v; uint4 q; } o;
  o.v[0] = (__bf16)a.x; o.v[1] = (__bf16)a.y; o.v[2] = (__bf16)a.z; o.v[3] = (__bf16)a.w;
  o.v[4] = (__bf16)b.x; o.v[5] = (__bf16)b.y; o.v[6] = (__bf16)b.z; o.v[7] = (__bf16)b.w;
  *(uint4*)(dst + i) = o.q;
}

// ---------------- big-tile GEMM template: 256x128, BK=64, 8 waves ---------
// 3-buffer, 2-tiles-ahead staging with counted vmcnt (T4, attn-proven):
// per wave 6 gload_lds/tile; at tile top 12 in flight -> vmcnt(6) waits for
// exactly tile t's loads; vmcnt(0) only at the last tile. Buffer (kt+2)%3 was
// last read in tile kt-1 (all reads precede B1 of tile kt) -> stage-after-B1
// is race-free. 2 phases per tile with per-phase {8 ds_read | stage | 16 MFMA}
// interleave + B2 pacing.
template <int MODE, int BXN>
__global__ __launch_bounds__(512, 2) void k_gemm_big(
    const u16* __restrict__ A, const u16* __restrict__ W,
    const float* __restrict__ bias, float* __restrict__ Cout,
    u16* __restrict__ Qo, u16* __restrict__ Ko, u16* __restrict__ Vo) {
  __shared__ __align__(16) u16 LDS[3][6 * 4096];  // 144 KB

  const int t = threadIdx.x;
  const int lane = t & 63;
  const int w = t >> 6;
  const int wm = w >> 1;
  const int wn = w & 1;
  const int lr = lane & 15;
  const int hi = lane >> 4;

  const int TOT = BXN * 32;
  const int flat = blockIdx.x;
  const int nb = (flat & 7) * (TOT >> 3) + (flat >> 3);
  const int by = nb / BXN;
  const int bx = nb - by * BXN;
  const int m0 = by * 256;
  const int n0 = bx * 128;

  const int tt = t & 255;
  const int g = t >> 8;
  const int tu = (tt & 15) ^ (tt >> 4);
  const int sro = (tu >> 3) * 32 + (tt >> 4);
  const int scol = (tu & 7) * 8;

  auto STAGE = [&](int buf, int kt, int pLo, int pHi) {
    for (int p = pLo; p < pHi; ++p) {
      int st = p * 2 + g;
      const u16* base = (st < 4) ? (A + (size_t)(m0 + st * 64) * 1024)
                                 : (W + (size_t)(n0 + (st - 4) * 64) * 1024);
#pragma unroll
      for (int i = 0; i < 2; ++i)
        gload_lds16(base + (size_t)(sro + i * 16) * 1024 + kt * 64 + scol,
                    &LDS[buf][st * 4096 + i * 2048 + tt * 8]);
    }
  };

  f32x4 acc[4][4] = {};

  STAGE(0, 0, 0, 3);
  STAGE(1, 1, 0, 3);

  for (int kt = 0; kt < 16; ++kt) {
    const int cur = kt % 3;
    const int nxt = (kt + 2) % 3;
    if (kt < 15) asm volatile("s_waitcnt vmcnt(6)" ::: "memory");
    else         asm volatile("s_waitcnt vmcnt(0)" ::: "memory");
    __builtin_amdgcn_sched_barrier(0);
    __builtin_amdgcn_s_barrier();          // B1: tile kt resident; buf nxt free
    __builtin_amdgcn_sched_barrier(0);

    const u16* ab = &LDS[cur][wm * 4096];
    const u16* bb = &LDS[cur][(4 + wn) * 4096];

#pragma unroll
    for (int ks = 0; ks < 2; ++ks) {
      bf16x8 af[4], bfr[4];
#pragma unroll
      for (int mi = 0; mi < 4; ++mi)
        af[mi] = *(const bf16x8*)(ab + ((mi & 1) * 16 + lr) * 128 +
                                  (((ks * 4 + hi + 8 * (mi >> 1)) ^ lr) << 3));
#pragma unroll
      for (int ni = 0; ni < 4; ++ni)
        bfr[ni] = *(const bf16x8*)(bb + ((ni & 1) * 16 + lr) * 128 +
                                   (((ks * 4 + hi + 8 * (ni >> 1)) ^ lr) << 3));
      if (kt + 2 < 16) STAGE(nxt, kt + 2, ks ? 2 : 0, ks ? 3 : 2);
      asm volatile("s_waitcnt lgkmcnt(0)" ::: "memory");
      __builtin_amdgcn_sched_barrier(0);
      __builtin_amdgcn_s_setprio(1);
#pragma unroll
      for (int mi = 0; mi < 4; ++mi)
#pragma unroll
        for (int ni = 0; ni < 4; ++ni)
          acc[mi][ni] = mfma16(bfr[ni], af[mi], acc[mi][ni]);  // swapped
      __builtin_amdgcn_s_setprio(0);
      __builtin_amdgcn_sched_barrier(0);
      if (ks == 0) __builtin_amdgcn_s_barrier();   // B2: phase pacing
    }
  }

  f32x4 bv[4];
#pragma unroll
  for (int ni = 0; ni < 4; ++ni)
    bv[ni] = *(const f32x4*)(bias + n0 + wn * 64 + ni * 16 + hi * 4);

  if (MODE == 0) {
    const int N = BXN * 128;
#pragma unroll
    for (int mi = 0; mi < 4; ++mi) {
      const int m = m0 + wm * 64 + mi * 16 + lr;
#pragma unroll
      for (int ni = 0; ni < 4; ++ni) {
        f32x4 o = acc[mi][ni] + bv[ni];
        *(f32x4*)(Cout + (size_t)m * N + n0 + wn * 64 + ni * 16 + hi * 4) = o;
      }
    }
  } else {
    const int bb16 = m0 >> 11;
    const int sb = (m0 & 2047) + wm * 64;
    const int which = n0 >> 10;
    const int h = ((n0 & 1023) >> 6) + wn;

    if (which < 2) {
      const float scl = (which == 0) ? QSCALE : 1.0f;
      u16* dst = ((which == 0) ? Qo : Ko) + ((size_t)(bb16 * 16 + h) * 2048) * 64;
#pragma unroll
      for (int mi = 0; mi < 4; ++mi) {
        const int s = sb + mi * 16 + lr;
#pragma unroll
        for (int ni = 0; ni < 4; ++ni) {
          bf16x4 pk;
#pragma unroll
          for (int j = 0; j < 4; ++j)
            pk[j] = (__bf16)((acc[mi][ni][j] + bv[ni][j]) * scl);
          *(bf16x4*)(dst + (size_t)s * 64 + ni * 16 + hi * 4) = pk;
        }
      }
    } else {
      __syncthreads();
      u16* scr = &LDS[0][0] + w * 4608;
#pragma unroll
      for (int mi = 0; mi < 4; ++mi)
#pragma unroll
        for (int ni = 0; ni < 4; ++ni)
#pragma unroll
          for (int j = 0; j < 4; ++j) {
            union { __bf16 b; u16 u; } cv;
            cv.b = (__bf16)(acc[mi][ni][j] + bv[ni][j]);
            scr[(ni * 16 + hi * 4 + j) * 72 + mi * 16 + lr] = cv.u;
          }
      asm volatile("s_waitcnt lgkmcnt(0)" ::: "memory");
      __builtin_amdgcn_sched_barrier(0);
      u16* dst = Vo + ((size_t)((bb16 * 16 + h) * 64 + lane)) * 2048 + sb;
#pragma unroll
      for (int mc = 0; mc < 8; ++mc) {
        bf16x8 vv = *(const bf16x8*)(scr + lane * 72 + mc * 8);
        *(bf16x8*)(dst + mc * 8) = vv;
      }
    }
  }
}

// ---------------- flash attention (round-11 verbatim: known 91.2 us) ------
__global__ __launch_bounds__(256, 4) void k_attn(const u16* __restrict__ Q,
                                                 const u16* __restrict__ K,
                                                 const u16* __restrict__ Vt,
                                                 u16* __restrict__ ctx) {
  __shared__ __align__(16) u16 Ks[2][64 * 64];
  __shared__ __align__(16) u16 Vs[2][64 * 64];

  const int t = threadIdx.x;
  const int lane = t & 63;
  const int w = t >> 6;
  const int r31 = lane & 31;
  const int hw = lane >> 5;

  const int bid = blockIdx.x;
  const int nb = (bid & 7) * 128 + (bid >> 3);
  const int bh = nb >> 4;
  const int q0 = (nb & 15) * 128;
  const int phase = (((bid >> 8) ^ (bid >> 3)) & 3) * 8;

  const u16* qp = Q + (size_t)bh * 2048 * 64;
  const u16* kp = K + (size_t)bh * 2048 * 64;
  const u16* vp = Vt + (size_t)bh * 64 * 2048;

  const int tu = (t & 15) ^ (t >> 4);
  const int srow = (tu >> 3) * 32 + (t >> 4);
  const int scol = (tu & 7) * 8;

#pragma unroll
  for (int i = 0; i < 2; i++)
    gload_lds16(kp + (size_t)(phase * 64 + srow + i * 16) * 64 + scol,
                Ks[0] + i * 2048 + t * 8);
#pragma unroll
  for (int i = 0; i < 2; i++)
    gload_lds16(vp + (size_t)(srow + i * 16) * 2048 + phase * 64 + scol,
                Vs[0] + i * 2048 + t * 8);

  bf16x8 aq[4];
  const u16* qrow = qp + (size_t)(q0 + w * 32 + r31) * 64 + hw * 8;
#pragma unroll
  for (int kd = 0; kd < 4; kd++) aq[kd] = *(const bf16x8*)(qrow + kd * 16);

  bf16x8 ones;
#pragma unroll
  for (int e = 0; e < 8; e++) ones[e] = (__bf16)1.0f;
  const f32x16 Z = {};

  f32x16 o0 = {}, o1 = {}, l_acc = {};

  for (int it = 0; it < 32; it++) {
    const int cur = it & 1;
    asm volatile("s_waitcnt vmcnt(0)" ::: "memory");
    __builtin_amdgcn_sched_barrier(0);
    __builtin_amdgcn_s_barrier();   // tile ready everywhere; prev buf reads done
    __builtin_amdgcn_sched_barrier(0);

    if (it + 1 < 32) {
      const int ktn = ((it + 1 + phase) & 31) * 64;
      u16* kd_ = Ks[cur ^ 1];
      u16* vd_ = Vs[cur ^ 1];
#pragma unroll
      for (int i = 0; i < 2; i++)
        gload_lds16(kp + (size_t)(ktn + srow + i * 16) * 64 + scol,
                    kd_ + i * 2048 + t * 8);
#pragma unroll
      for (int i = 0; i < 2; i++)
        gload_lds16(vp + (size_t)(srow + i * 16) * 2048 + ktn + scol,
                    vd_ + i * 2048 + t * 8);
    }

    const u16* kb = Ks[cur];
    const u16* vb = Vs[cur];

    __builtin_amdgcn_s_setprio(1);
    f32x16 s0, s1;
    {
      bf16x8 ka0 = *(const bf16x8*)(kb + r31 * 128 + (((hw) ^ (r31 & 15)) << 3));
      bf16x8 ka1 = *(const bf16x8*)(kb + r31 * 128 + (((8 + hw) ^ (r31 & 15)) << 3));
      s0 = mfma32(ka0, aq[0], Z);
      s1 = mfma32(ka1, aq[0], Z);
    }
#pragma unroll
    for (int kd = 1; kd < 4; kd++) {
      int sl0 = (((kd * 2 + hw) ^ (r31 & 15)) << 3);
      int sl1 = (((8 + kd * 2 + hw) ^ (r31 & 15)) << 3);
      bf16x8 ka0 = *(const bf16x8*)(kb + r31 * 128 + sl0);
      bf16x8 ka1 = *(const bf16x8*)(kb + r31 * 128 + sl1);
      s0 = mfma32(ka0, aq[kd], s0);
      s1 = mfma32(ka1, aq[kd], s1);
    }
    __builtin_amdgcn_s_setprio(0);

#pragma unroll
    for (int e = 0; e < 16; e++) {
      s0[e] = __builtin_amdgcn_exp2f(s0[e]);
      s1[e] = __builtin_amdgcn_exp2f(s1[e]);
    }

    __builtin_amdgcn_s_setprio(1);
#pragma unroll
    for (int tile = 0; tile < 2; tile++) {
      f32x16 st = tile ? s1 : s0;
      unsigned pk[8];
#pragma unroll
      for (int p = 0; p < 8; p++) {
        union { __bf16 h[2]; unsigned u; } cv;
        cv.h[0] = (__bf16)st[2 * p];
        cv.h[1] = (__bf16)st[2 * p + 1];
        pk[p] = cv.u;
      }
#pragma unroll
      for (int c = 0; c < 2; c++) {
        u32x2 ra = __builtin_amdgcn_permlane32_swap(pk[4 * c], pk[4 * c + 2], false, false);
        u32x2 rb = __builtin_amdgcn_permlane32_swap(pk[4 * c + 1], pk[4 * c + 3], false, false);
        union { unsigned u[4]; bf16x8 v; } pf;
        pf.u[0] = ra[0]; pf.u[1] = rb[0]; pf.u[2] = ra[1]; pf.u[3] = rb[1];
        const int kap = tile * 2 + c;
        int slv0 = (((kap * 2 + hw) ^ (r31 & 15)) << 3);
        int slv1 = (((8 + kap * 2 + hw) ^ (r31 & 15)) << 3);
        bf16x8 v0 = *(const bf16x8*)(vb + r31 * 128 + slv0);
        bf16x8 v1 = *(const bf16x8*)(vb + r31 * 128 + slv1);
        o0 = mfma32(v0, pf.v, o0);
        o1 = mfma32(v1, pf.v, o1);
        l_acc = mfma32(ones, pf.v, l_acc);
      }
    }
    __builtin_amdgcn_s_setprio(0);
  }

  const int bb = bh >> 4, h = bh & 15;
  const float inv = 1.0f / l_acc[0];
  const size_t base = (size_t)(bb * 2048 + q0 + w * 32 + r31) * 1024 + h * 64;
#pragma unroll
  for (int g = 0; g < 4; g++) {
    bf16x4 p0, p1;
#pragma unroll
    for (int j = 0; j < 4; j++) {
      p0[j] = (__bf16)(o0[g * 4 + j] * inv);
      p1[j] = (__bf16)(o1[g * 4 + j] * inv);
    }
    *(bf16x4*)(ctx + base + g * 8 + hw * 4) = p0;
    *(bf16x4*)(ctx + base + 32 + g * 8 + hw * 4) = p1;
  }
}

extern "C" void kernel_launch(void* const* d_in, const int* in_sizes, int n_in,
                              void* d_out, int out_size, void* d_ws, size_t ws_size,
                              hipStream_t stream) {
  const float* x = (const float*)d_in[0];
  const float* qkv_w = (const float*)d_in[1];
  const float* qkv_b = (const float*)d_in[2];
  const float* out_w = (const float*)d_in[3];
  const float* out_b = (const float*)d_in[4];
  float* out = (float*)d_out;
  char* ws = (char*)d_ws;

  u16* xb    = (u16*)(ws + 0);          // 16 MB (later: ctx)
  u16* wqkvb = (u16*)(ws + 16777216);   // 6 MB
  u16* wob   = (u16*)(ws + 23068672);   // 2 MB
  u16* Qb    = (u16*)(ws + 25165824);   // 16 MB
  u16* Kb    = (u16*)(ws + 41943040);   // 16 MB
  u16* Vtb   = (u16*)(ws + 58720256);   // 16 MB, [BH,64,S]
  u16* ctx   = xb;

  k_cvt3<<<6144, 256, 0, stream>>>(x, xb, 8388608,
                                   qkv_w, wqkvb, 3145728,
                                   out_w, wob, 1048576);

  k_gemm_big<1, 24><<<768, 512, 0, stream>>>(xb, wqkvb, qkv_b, nullptr,
                                             Qb, Kb, Vtb);
  k_attn<<<1024, 256, 0, stream>>>(Qb, Kb, Vtb, ctx);
  k_gemm_big<0, 8><<<256, 512, 0, stream>>>(ctx, wob, out_b, out,
                                            nullptr, nullptr, nullptr);
}